// Round 4
// baseline (224.183 us; speedup 1.0000x reference)
//
#include <hip/hip_runtime.h>
#include <math.h>

#define CIN  3
#define COUT 24
#define KS   3
#define DIN  16
#define HIN  128
#define WIN  128
#define HOUT 126
#define DOUT 14

// ---------------- Phase 1: conv3d + min over depth (pre-bias) ----------------
// grid = 3 co-groups x 16 batches x 32 h-tiles = 1536 blocks, 2 waves each.
// Wave 0: dp 0..6, wave 1: dp 7..13; min-combined via LDS at the end.
// Lane = 16 w-chunks x 4 h-rows; each lane computes acc[8co][8pix].
// Weights transposed in LDS: wT[t][co] so one ds_read_b128 = 4 co-weights.
__global__ __launch_bounds__(128) void conv_min_kernel(
    const float* __restrict__ x,
    const float* __restrict__ wgt,
    float* __restrict__ y)        // y = d_out, [16][24][126][126], pre-bias conv-min
{
    __shared__ float  wT[81 * 24];      // 7776 B
    __shared__ float4 mred[16 * 64];    // 16 KB: wave1's m tile, [slot][lane]

    const int tid  = threadIdx.x;
    const int wave = tid >> 6;
    const int lane = tid & 63;

    // stage transposed weights: wT[t*24+co] = wgt[co*81+t]
    for (int idx = tid; idx < 81 * 24; idx += 128) {
        int t  = idx / 24;
        int co = idx - t * 24;
        wT[idx] = wgt[co * 81 + t];
    }
    __syncthreads();

    const int g  = blockIdx.x % 3;            // co-group (co = g*8 .. g*8+7)
    int tmp      = blockIdx.x / 3;
    const int b  = tmp & 15;
    const int ht = tmp >> 4;                  // 0..31
    const int h0 = ht * 4;

    const int chunk = lane & 15;              // w-chunk: pixels w0..w0+7
    const int hh    = lane >> 4;              // 0..3
    const int hout  = h0 + hh;                // output row, valid < 126
    const bool hvalid = hout < HOUT;
    const int w0    = chunk * 8;

    // lane-row base offset within a (ci,d) slice; clamp invalid rows to row 0
    const int row_off = (hvalid ? hout : 0) * WIN + w0;
    const float* xb = x + (size_t)b * (CIN * DIN * HIN * WIN);

    // halo float2: chunk 15 would read w=128,129 (OOB) -> re-read +4 (dup, masked)
    const int halo_off = (chunk == 15) ? 4 : 8;

    float m[8][8];
    #pragma unroll
    for (int c = 0; c < 8; ++c)
        #pragma unroll
        for (int p = 0; p < 8; ++p) m[c][p] = 3.4e38f;

    const int dpBeg = wave ? 7 : 0;
    const int dpEnd = wave ? DOUT : 7;

    #pragma unroll 1
    for (int dp = dpBeg; dp < dpEnd; ++dp) {
        float acc[8][8];
        #pragma unroll
        for (int c = 0; c < 8; ++c)
            #pragma unroll
            for (int p = 0; p < 8; ++p) acc[c][p] = 0.0f;

        #pragma unroll 1
        for (int ci = 0; ci < CIN; ++ci) {
            #pragma unroll 1
            for (int kd = 0; kd < KS; ++kd) {
                const float* xsl =
                    xb + (size_t)(ci * DIN + dp + kd) * (HIN * WIN) + row_off;
                #pragma unroll
                for (int kh = 0; kh < KS; ++kh) {
                    const float* xr = xsl + kh * WIN;
                    // 10 px values: 8 pixels + 2 halo
                    float px[10];
                    *(float4*)&px[0] = *(const float4*)(xr);
                    *(float4*)&px[4] = *(const float4*)(xr + 4);
                    float2 h2 = *(const float2*)(xr + halo_off);
                    px[8] = h2.x; px[9] = h2.y;

                    const float* wr = &wT[((ci * 3 + kd) * 3 + kh) * 3 * 24 + g * 8];
                    #pragma unroll
                    for (int kw = 0; kw < 3; ++kw) {
                        float wv[8];
                        *(float4*)&wv[0] = *(const float4*)(wr + kw * 24);
                        *(float4*)&wv[4] = *(const float4*)(wr + kw * 24 + 4);
                        #pragma unroll
                        for (int c = 0; c < 8; ++c)
                            #pragma unroll
                            for (int p = 0; p < 8; ++p)
                                acc[c][p] = fmaf(wv[c], px[p + kw], acc[c][p]);
                    }
                }
            }
        }
        #pragma unroll
        for (int c = 0; c < 8; ++c)
            #pragma unroll
            for (int p = 0; p < 8; ++p)
                m[c][p] = fminf(m[c][p], acc[c][p]);
    }

    // ---- cross-wave min combine through LDS ----
    if (wave == 1) {
        #pragma unroll
        for (int c = 0; c < 8; ++c)
            #pragma unroll
            for (int pq = 0; pq < 2; ++pq)
                mred[(c * 2 + pq) * 64 + lane] =
                    make_float4(m[c][pq*4+0], m[c][pq*4+1], m[c][pq*4+2], m[c][pq*4+3]);
    }
    __syncthreads();
    if (wave == 1) return;

    #pragma unroll
    for (int c = 0; c < 8; ++c) {
        #pragma unroll
        for (int pq = 0; pq < 2; ++pq) {
            float4 o = mred[(c * 2 + pq) * 64 + lane];
            m[c][pq*4+0] = fminf(m[c][pq*4+0], o.x);
            m[c][pq*4+1] = fminf(m[c][pq*4+1], o.y);
            m[c][pq*4+2] = fminf(m[c][pq*4+2], o.z);
            m[c][pq*4+3] = fminf(m[c][pq*4+3], o.w);
        }
    }

    // store conv-min (pre-bias); invalid rows/cols masked
    float* yb = y + ((size_t)b * COUT + g * 8) * (HOUT * HOUT)
                  + (size_t)hout * HOUT + w0;
    #pragma unroll
    for (int c = 0; c < 8; ++c) {
        #pragma unroll
        for (int p = 0; p < 8; ++p) {
            if (hvalid && (w0 + p) < HOUT)
                yb[(size_t)c * (HOUT * HOUT) + p] = m[c][p];
        }
    }
}

// ---------------- Phase 2: bias + softmax over channels, in place ----------------
__global__ __launch_bounds__(128) void bias_softmax_kernel(
    const float* __restrict__ bias,
    float* __restrict__ y)
{
    const int w = threadIdx.x;
    if (w >= HOUT) return;
    const int h = blockIdx.x;
    const int b = blockIdx.y;

    float* p = y + (size_t)b * COUT * (HOUT * HOUT) + (size_t)h * HOUT + w;

    float v[COUT];
    float mx = -3.4e38f;
    #pragma unroll
    for (int c = 0; c < COUT; ++c) {
        v[c] = p[(size_t)c * (HOUT * HOUT)] + bias[c];
        mx = fmaxf(mx, v[c]);
    }
    float sum = 0.0f;
    #pragma unroll
    for (int c = 0; c < COUT; ++c) {
        v[c] = __expf(v[c] - mx);
        sum += v[c];
    }
    const float r = 1.0f / sum;
    #pragma unroll
    for (int c = 0; c < COUT; ++c) {
        p[(size_t)c * (HOUT * HOUT)] = v[c] * r;
    }
}

extern "C" void kernel_launch(void* const* d_in, const int* in_sizes, int n_in,
                              void* d_out, int out_size, void* d_ws, size_t ws_size,
                              hipStream_t stream) {
    const float* x    = (const float*)d_in[0];
    const float* wgt  = (const float*)d_in[1];
    const float* bias = (const float*)d_in[2];
    float* out        = (float*)d_out;

    conv_min_kernel<<<dim3(3 * 16 * 32), dim3(128), 0, stream>>>(x, wgt, out);
    bias_softmax_kernel<<<dim3(HOUT, 16), dim3(128), 0, stream>>>(bias, out);
}

// Round 7
// 82.778 us; speedup vs baseline: 2.7083x; 2.7083x over previous
//
#include <hip/hip_runtime.h>
#include <math.h>

#define CIN 3
#define DIN 16
#define HIN 128
#define WIN 128
#define COUT 24
#define HOUT 126
#define DOUT 14

using f16x8 = __attribute__((ext_vector_type(8))) _Float16;
using f32x4 = __attribute__((ext_vector_type(4))) float;

// 162 logical im-rows per depth slice, row stride 18 halves (36 B) so that the
// 4 kg-groups' column-gathers hit disjoint bank octets: bank=(9*row+cl/2)%32.
#define ROWSTRIDE 18
#define SLOT_HALVES (162 * ROWSTRIDE)              // 2916
#define LDS_HALVES  (4 * SLOT_HALVES + 96)         // + overread tail (rows 162..166)

// One block: 4 waves, 16 output rows x 16 cols x 24 co, all 14 dp (min in-reg).
// LDS ring: 4 depth-slices of im-rows [hrow 0..17][ci][kw] -> 162 rows of 16 px.
// Tile (rel_h) K-chunk rows are CONTIGUOUS: rows 9*rel_h .. +26 (k = kh*9+ci*3+kw).
// A-frag: plain strided u16 LDS reads (ABLATION of the tr-read asm path).
__global__ __launch_bounds__(256) void conv3d_min_softmax_mfma(
    const float* __restrict__ x,
    const float* __restrict__ wgt,
    const float* __restrict__ bias,
    float* __restrict__ out)
{
    __shared__ _Float16 imX[LDS_HALVES];

    const int tid  = threadIdx.x;
    const int wv   = tid >> 6;
    const int lane = tid & 63;
    const int cl   = lane & 15;   // A: px-lane | B/C: co-lane
    const int kg   = lane >> 4;   // A/B: k-group | C: px-row-group

    const int wchunk = blockIdx.x;
    const int band   = blockIdx.y;
    const int b      = blockIdx.z;
    const int w0 = (wchunk < 7) ? wchunk * 16 : 110;   // overlap chunk: identical math, benign
    const int h0 = (band   < 7) ? band   * 16 : 110;

    const float* xb = x + (size_t)b * (CIN * DIN * HIN * WIN);

    // zero slot 3 + tail: dp=0 overreads (k>=27) must see finite data
    for (int i = 3 * SLOT_HALVES + tid; i < LDS_HALVES; i += 256)
        imX[i] = (_Float16)0.f;

    // ---- B-fragments (weights) in regs; k-order = kh*9 + ci*3 + kw; pads -> 0
    f16x8 bw[3][2];   // [kd][co-half]
    #pragma unroll
    for (int kd = 0; kd < 3; ++kd)
      #pragma unroll
      for (int hf = 0; hf < 2; ++hf)
        #pragma unroll
        for (int j = 0; j < 8; ++j) {
          int k  = kg * 8 + j;
          int co = hf * 16 + cl;
          float wvv = 0.f;
          if (k < 27 && co < 24) {
            int kh = k / 9, rem = k - kh * 9, ci = rem / 3, kw = rem - ci * 3;
            wvv = wgt[((co * 3 + ci) * 3 + kd) * 9 + kh * 3 + kw];
          }
          bw[kd][hf][j] = (_Float16)wvv;
        }

    const float bias0 = bias[cl];
    const float bias1 = (cl < 8) ? bias[16 + cl] : 0.f;

    // ---- per-thread builder offsets (invariant over slice s)
    int goff[11];   // global offset within a slice
    int lidx[11];   // LDS index within a slot (row*18 + px)
    int eidx[11];
    #pragma unroll
    for (int it = 0; it < 11; ++it) {
      int e = tid + it * 256;
      eidx[it] = e;
      int ec = (e < 2592) ? e : 0;
      int hrow = ec / 144, e2 = ec - hrow * 144;
      int ci   = e2 / 48,  e3 = e2 - ci * 48;
      int kw   = e3 >> 4,  px = e3 & 15;
      goff[it] = (ci * DIN) * (HIN * WIN) + (h0 + hrow) * WIN + (w0 + kw + px);
      lidx[it] = (hrow * 9 + ci * 3 + kw) * ROWSTRIDE + px;
    }

    // ---- preload slices 0..2 into slots 0..2
    #pragma unroll 1
    for (int s = 0; s < 3; ++s) {
      #pragma unroll
      for (int it = 0; it < 11; ++it) {
        if (eidx[it] < 2592) {
          float v = xb[goff[it] + s * (HIN * WIN)];
          imX[s * SLOT_HALVES + lidx[it]] = (_Float16)v;
        }
      }
    }
    __syncthreads();

    // ---- main dp loop: min-accumulate conv(dp) in C-frag registers
    float mn[4][2][4];
    #pragma unroll
    for (int t = 0; t < 4; ++t)
      #pragma unroll
      for (int hf = 0; hf < 2; ++hf)
        #pragma unroll
        for (int j = 0; j < 4; ++j) mn[t][hf][j] = 3.4e38f;

    #pragma unroll 1
    for (int dp = 0; dp < DOUT; ++dp) {
      // issue next-slice loads early (hide HBM under MFMA)
      float stash[11];
      const int s = dp + 3;
      const bool doBuild = (s < DIN);
      if (doBuild) {
        #pragma unroll
        for (int it = 0; it < 11; ++it)
          if (eidx[it] < 2592)
            stash[it] = xb[goff[it] + s * (HIN * WIN)];
      }

      // compute: 4 tiles x (3 kd chained) x 2 co-halves
      #pragma unroll
      for (int t = 0; t < 4; ++t) {
        const int rel_h = wv * 4 + t;
        const int rowbase = (rel_h * 9 + kg * 8) * ROWSTRIDE + cl;

        f16x8 A[3];
        #pragma unroll
        for (int kd = 0; kd < 3; ++kd) {
          const _Float16* ap = &imX[((dp + kd) & 3) * SLOT_HALVES + rowbase];
          #pragma unroll
          for (int j = 0; j < 8; ++j)
            A[kd][j] = ap[j * ROWSTRIDE];      // element (row rowbase+j, col cl)
        }

        f32x4 z = {0.f, 0.f, 0.f, 0.f};
        f32x4 acc0 = __builtin_amdgcn_mfma_f32_16x16x32_f16(A[0], bw[0][0], z, 0, 0, 0);
        f32x4 acc1 = __builtin_amdgcn_mfma_f32_16x16x32_f16(A[0], bw[0][1], z, 0, 0, 0);
        acc0 = __builtin_amdgcn_mfma_f32_16x16x32_f16(A[1], bw[1][0], acc0, 0, 0, 0);
        acc1 = __builtin_amdgcn_mfma_f32_16x16x32_f16(A[1], bw[1][1], acc1, 0, 0, 0);
        acc0 = __builtin_amdgcn_mfma_f32_16x16x32_f16(A[2], bw[2][0], acc0, 0, 0, 0);
        acc1 = __builtin_amdgcn_mfma_f32_16x16x32_f16(A[2], bw[2][1], acc1, 0, 0, 0);

        #pragma unroll
        for (int j = 0; j < 4; ++j) {
          mn[t][0][j] = fminf(mn[t][0][j], acc0[j]);
          mn[t][1][j] = fminf(mn[t][1][j], acc1[j]);
        }
      }

      // write staged slice (slot dp+3 is disjoint from slots dp..dp+2)
      if (doBuild) {
        #pragma unroll
        for (int it = 0; it < 11; ++it)
          if (eidx[it] < 2592)
            imX[(s & 3) * SLOT_HALVES + lidx[it]] = (_Float16)stash[it];
      }
      __syncthreads();
    }

    // ---- fused bias + softmax over channels (cross-lane over 16-lane group)
    float* ob = out + (size_t)b * COUT * HOUT * HOUT;
    #pragma unroll
    for (int t = 0; t < 4; ++t) {
      const int h = h0 + wv * 4 + t;
      #pragma unroll
      for (int j = 0; j < 4; ++j) {
        float v0 = mn[t][0][j] + bias0;
        float v1 = (cl < 8) ? (mn[t][1][j] + bias1) : -3.4e38f;
        float mx = fmaxf(v0, v1);
        #pragma unroll
        for (int msk = 1; msk < 16; msk <<= 1)
          mx = fmaxf(mx, __shfl_xor(mx, msk));
        float e0 = __expf(v0 - mx);
        float e1 = (cl < 8) ? __expf(v1 - mx) : 0.f;
        float sm = e0 + e1;
        #pragma unroll
        for (int msk = 1; msk < 16; msk <<= 1)
          sm += __shfl_xor(sm, msk);
        float r = 1.f / sm;
        const int w = w0 + kg * 4 + j;
        ob[((size_t)cl * HOUT + h) * HOUT + w] = e0 * r;
        if (cl < 8)
          ob[((size_t)(16 + cl) * HOUT + h) * HOUT + w] = e1 * r;
      }
    }
}

extern "C" void kernel_launch(void* const* d_in, const int* in_sizes, int n_in,
                              void* d_out, int out_size, void* d_ws, size_t ws_size,
                              hipStream_t stream) {
    const float* x    = (const float*)d_in[0];
    const float* wgt  = (const float*)d_in[1];
    const float* bias = (const float*)d_in[2];
    float* out        = (float*)d_out;

    dim3 grid(8, 8, 16);   // (wchunk, band, b)
    dim3 block(256);
    conv3d_min_softmax_mfma<<<grid, block, 0, stream>>>(x, wgt, bias, out);
}